// Round 1
// baseline (212.396 us; speedup 1.0000x reference)
//
#include <hip/hip_runtime.h>

// YOLO-v1 loss, fp32, N=16384, S=7, B=2, C=20 → 30 floats/cell, 802816 cells.
// Memory-bound streaming reduction: stage 256 cells/block into LDS with
// coalesced float4 loads, thread-per-cell math, block reduce, atomicAdd.

constexpr int S = 7;
constexpr int FPC = 30;          // floats per cell
constexpr int BLK = 256;         // cells per block == threads per block
constexpr float STEP = 1.0f / 7.0f;
constexpr float EPS = 1e-10f;

__global__ __launch_bounds__(BLK) void yolo_loss_kernel(
    const float* __restrict__ pred,
    const float* __restrict__ target,
    float* __restrict__ out,
    float invN) {
  __shared__ float sp[BLK * FPC];   // 30720 B
  __shared__ float st[BLK * FPC];   // 30720 B
  __shared__ float wsum[BLK / 64];

  const int tid = threadIdx.x;
  const int cell0 = blockIdx.x * BLK;

  // ---- stage 256 cells of pred & target into LDS (coalesced float4) ----
  // base byte offset = cell0*120, divisible by 16 since BLK=256.
  const float4* gp = (const float4*)(pred + (size_t)cell0 * FPC);
  const float4* gt = (const float4*)(target + (size_t)cell0 * FPC);
  float4* lp = (float4*)sp;
  float4* lt = (float4*)st;
  constexpr int NV = BLK * FPC / 4;  // 1920 float4s per array
  #pragma unroll
  for (int i = 0; i < NV; i += BLK) {
    int idx = i + tid;
    if (idx < NV) {
      lp[idx] = gp[idx];
      lt[idx] = gt[idx];
    }
  }
  __syncthreads();

  // ---- per-cell loss ----
  const int cell = cell0 + tid;
  const float* p = sp + tid * FPC;
  const float* t = st + tid * FPC;
  const float gx = (float)(cell % S);
  const float gy = (float)((cell / S) % S);
  const float mask = (t[9] > 0.0f) ? 1.0f : 0.0f;

  float iou[2];
  #pragma unroll
  for (int b = 0; b < 2; ++b) {
    const float* pb = p + 5 * b;
    const float* tb = t + 5 * b;
    // _convert_boxes: x0=(x+gx)*STEP - w/2, clip all 4 at 0
    float px = fmaxf((pb[0] + gx) * STEP - pb[2] * 0.5f, 0.0f);
    float py = fmaxf((pb[1] + gy) * STEP - pb[3] * 0.5f, 0.0f);
    float pw = fmaxf(pb[2], 0.0f);
    float ph = fmaxf(pb[3], 0.0f);
    float tx = fmaxf((tb[0] + gx) * STEP - tb[2] * 0.5f, 0.0f);
    float ty = fmaxf((tb[1] + gy) * STEP - tb[3] * 0.5f, 0.0f);
    float tw = fmaxf(tb[2], 0.0f);
    float th = fmaxf(tb[3], 0.0f);
    float iw = fmaxf(pw + tw - (fmaxf(px + pw, tx + tw) - fminf(px, tx)), 0.0f);
    float ih = fmaxf(ph + th - (fmaxf(py + ph, ty + th) - fminf(py, ty)), 0.0f);
    float inter = iw * ih;
    float uni = pw * ph + tw * th - inter;
    iou[b] = inter / (uni + EPS);
  }
  // jnp.argmax: first max wins → box 0 on tie
  const int best = (iou[1] > iou[0]) ? 1 : 0;

  float loss = 0.0f;
  #pragma unroll
  for (int b = 0; b < 2; ++b) {
    const float* pb = p + 5 * b;
    const float* tb = t + 5 * b;
    float obj = (b == best) ? mask : 0.0f;
    float d0 = pb[0] - tb[0];
    float d1 = pb[1] - tb[1];
    float d2 = pb[2] - tb[2];
    float d3 = pb[3] - tb[3];
    loss += 5.0f * obj * (d0 * d0 + d1 * d1 + d2 * d2 + d3 * d3);  // coord
    float dc = pb[4] - iou[b];
    loss += obj * dc * dc;                                         // conf
    loss += 0.5f * (1.0f - obj) * pb[4] * pb[4];                   // noobj
  }
  float cls = 0.0f;
  #pragma unroll
  for (int k = 10; k < 30; ++k) {
    float d = p[k] - t[k];
    cls += d * d;
  }
  loss += mask * cls;                                              // class

  // ---- reduce: wave shuffle → LDS → one atomic per block ----
  #pragma unroll
  for (int off = 32; off > 0; off >>= 1)
    loss += __shfl_down(loss, off, 64);
  const int wid = tid >> 6;
  if ((tid & 63) == 0) wsum[wid] = loss;
  __syncthreads();
  if (tid == 0) {
    float total = 0.0f;
    #pragma unroll
    for (int w = 0; w < BLK / 64; ++w) total += wsum[w];
    atomicAdd(out, total * invN);
  }
}

extern "C" void kernel_launch(void* const* d_in, const int* in_sizes, int n_in,
                              void* d_out, int out_size, void* d_ws, size_t ws_size,
                              hipStream_t stream) {
  const float* pred = (const float*)d_in[0];
  const float* target = (const float*)d_in[1];
  float* out = (float*)d_out;

  const int ncells = in_sizes[0] / FPC;      // 802816
  const int nblocks = ncells / BLK;          // 3136 (exact)
  const float invN = 1.0f / (float)(ncells / (S * S));  // 1/16384

  // d_out is poisoned 0xAA before every launch — zero it (capturable op).
  hipMemsetAsync(out, 0, sizeof(float), stream);
  yolo_loss_kernel<<<nblocks, BLK, 0, stream>>>(pred, target, out, invN);
}

// Round 2
// 212.289 us; speedup vs baseline: 1.0005x; 1.0005x over previous
//
#include <hip/hip_runtime.h>

// YOLO-v1 loss, fp32, N=16384, S=7, B=2, C=20 → 30 floats/cell, 802816 cells.
// R2: latency/occupancy-bound fix — no LDS staging. Thread-per-cell with
// direct float2 loads (cell stride 120 B is always 8B-aligned). Each wave
// streams a dense 7.68 KB span per array, so every 128B line is fully
// consumed via L1 — same bandwidth efficiency as LDS tiling, but 16 B LDS
// instead of 60.5 KB → occupancy is VGPR-bound (~5 waves/SIMD) instead of
// LDS-bound (2 waves/SIMD).

constexpr int S = 7;
constexpr int FPC = 30;          // floats per cell
constexpr int BLK = 256;
constexpr float STEP = 1.0f / 7.0f;
constexpr float EPS = 1e-10f;

__global__ __launch_bounds__(BLK) void yolo_loss_kernel(
    const float* __restrict__ pred,
    const float* __restrict__ target,
    float* __restrict__ out,
    float invN) {
  __shared__ float wsum[BLK / 64];

  const int tid = threadIdx.x;
  const int cell = blockIdx.x * BLK + tid;

  // ---- direct loads: 15 float2 per array (8B-aligned: 120*c % 8 == 0) ----
  const float2* p2 = (const float2*)(pred + (size_t)cell * FPC);
  const float2* t2 = (const float2*)(target + (size_t)cell * FPC);
  union Buf { float2 v[FPC / 2]; float f[FPC]; };
  Buf P, T;
  #pragma unroll
  for (int i = 0; i < FPC / 2; ++i) P.v[i] = p2[i];
  #pragma unroll
  for (int i = 0; i < FPC / 2; ++i) T.v[i] = t2[i];
  const float* p = P.f;
  const float* t = T.f;

  // ---- per-cell loss ----
  const float gx = (float)(cell % S);
  const float gy = (float)((cell / S) % S);
  const float mask = (t[9] > 0.0f) ? 1.0f : 0.0f;

  float iou[2];
  #pragma unroll
  for (int b = 0; b < 2; ++b) {
    const float* pb = p + 5 * b;
    const float* tb = t + 5 * b;
    // _convert_boxes: x0=(x+gx)*STEP - w/2, clip all 4 at 0
    float px = fmaxf((pb[0] + gx) * STEP - pb[2] * 0.5f, 0.0f);
    float py = fmaxf((pb[1] + gy) * STEP - pb[3] * 0.5f, 0.0f);
    float pw = fmaxf(pb[2], 0.0f);
    float ph = fmaxf(pb[3], 0.0f);
    float tx = fmaxf((tb[0] + gx) * STEP - tb[2] * 0.5f, 0.0f);
    float ty = fmaxf((tb[1] + gy) * STEP - tb[3] * 0.5f, 0.0f);
    float tw = fmaxf(tb[2], 0.0f);
    float th = fmaxf(tb[3], 0.0f);
    float iw = fmaxf(pw + tw - (fmaxf(px + pw, tx + tw) - fminf(px, tx)), 0.0f);
    float ih = fmaxf(ph + th - (fmaxf(py + ph, ty + th) - fminf(py, ty)), 0.0f);
    float inter = iw * ih;
    float uni = pw * ph + tw * th - inter;
    iou[b] = inter / (uni + EPS);
  }
  // jnp.argmax: first max wins → box 0 on tie
  const int best = (iou[1] > iou[0]) ? 1 : 0;

  float loss = 0.0f;
  #pragma unroll
  for (int b = 0; b < 2; ++b) {
    const float* pb = p + 5 * b;
    const float* tb = t + 5 * b;
    float obj = (b == best) ? mask : 0.0f;
    float d0 = pb[0] - tb[0];
    float d1 = pb[1] - tb[1];
    float d2 = pb[2] - tb[2];
    float d3 = pb[3] - tb[3];
    loss += 5.0f * obj * (d0 * d0 + d1 * d1 + d2 * d2 + d3 * d3);  // coord
    float dc = pb[4] - iou[b];
    loss += obj * dc * dc;                                         // conf
    loss += 0.5f * (1.0f - obj) * pb[4] * pb[4];                   // noobj
  }
  float cls = 0.0f;
  #pragma unroll
  for (int k = 10; k < 30; ++k) {
    float d = p[k] - t[k];
    cls += d * d;
  }
  loss += mask * cls;                                              // class

  // ---- reduce: wave shuffle → LDS → one atomic per block ----
  #pragma unroll
  for (int off = 32; off > 0; off >>= 1)
    loss += __shfl_down(loss, off, 64);
  const int wid = tid >> 6;
  if ((tid & 63) == 0) wsum[wid] = loss;
  __syncthreads();
  if (tid == 0) {
    float total = 0.0f;
    #pragma unroll
    for (int w = 0; w < BLK / 64; ++w) total += wsum[w];
    atomicAdd(out, total * invN);
  }
}

extern "C" void kernel_launch(void* const* d_in, const int* in_sizes, int n_in,
                              void* d_out, int out_size, void* d_ws, size_t ws_size,
                              hipStream_t stream) {
  const float* pred = (const float*)d_in[0];
  const float* target = (const float*)d_in[1];
  float* out = (float*)d_out;

  const int ncells = in_sizes[0] / FPC;      // 802816
  const int nblocks = ncells / BLK;          // 3136 (exact)
  const float invN = 1.0f / (float)(ncells / (S * S));  // 1/16384

  // d_out is poisoned 0xAA before every launch — zero it (capturable op).
  hipMemsetAsync(out, 0, sizeof(float), stream);
  yolo_loss_kernel<<<nblocks, BLK, 0, stream>>>(pred, target, out, invN);
}

// Round 3
// 207.114 us; speedup vs baseline: 1.0255x; 1.0250x over previous
//
#include <hip/hip_runtime.h>

// YOLO-v1 loss, fp32, N=16384, S=7, B=2, C=20 → 30 floats/cell, 802816 cells.
// R3: dense coalescing + high occupancy. Wave-private LDS staging, one
// 7.68 KB region per wave REUSED for pred then target (LDS ops are in-order
// within a wave → no __syncthreads between phases). Global loads are dense
// float4 (every 128B line fully consumed by one instruction), fixing R2's
// L1-line-thrash (FETCH grew to 125MB, 60 lines touched per VMEM instr).
// LDS/block ≈ 30.7 KB → 5 blocks/CU vs R1's 2.

constexpr int S = 7;
constexpr int FPC = 30;           // floats per cell
constexpr int BLK = 256;          // 4 waves
constexpr int WAVES = BLK / 64;
constexpr int TILE_F4 = 64 * FPC / 4;   // 480 float4 per wave tile
constexpr float STEP = 1.0f / 7.0f;
constexpr float EPS = 1e-10f;

__global__ __launch_bounds__(BLK) void yolo_loss_kernel(
    const float* __restrict__ pred,
    const float* __restrict__ target,
    float* __restrict__ out,
    float invN) {
  __shared__ float lds[WAVES][64 * FPC];   // 7680 B per wave region
  __shared__ float wsum[WAVES];

  const int tid = threadIdx.x;
  const int lane = tid & 63;
  const int wid = tid >> 6;
  const int cellw = blockIdx.x * BLK + wid * 64;  // wave's first cell
  const int cell = cellw + lane;

  float* myld = lds[wid];
  union Buf { float2 v[FPC / 2]; float f[FPC]; };
  Buf P, T;

  // ---- stage pred tile: dense float4, wave-private, no barrier ----
  {
    const float4* g = (const float4*)(pred + (size_t)cellw * FPC);
    float4* l = (float4*)myld;
    #pragma unroll
    for (int it = 0; it < (TILE_F4 + 63) / 64; ++it) {
      int idx = it * 64 + lane;
      if (idx < TILE_F4) l[idx] = g[idx];
    }
  }
  // ---- my cell's pred: 15× float2 from LDS (in-order per wave) ----
  {
    const float2* l2 = (const float2*)(myld + lane * FPC);
    #pragma unroll
    for (int i = 0; i < FPC / 2; ++i) P.v[i] = l2[i];
  }
  asm volatile("" ::: "memory");  // forbid compile-time reorder of next writes
  // ---- stage target tile into the SAME region, then read ----
  {
    const float4* g = (const float4*)(target + (size_t)cellw * FPC);
    float4* l = (float4*)myld;
    #pragma unroll
    for (int it = 0; it < (TILE_F4 + 63) / 64; ++it) {
      int idx = it * 64 + lane;
      if (idx < TILE_F4) l[idx] = g[idx];
    }
  }
  {
    const float2* l2 = (const float2*)(myld + lane * FPC);
    #pragma unroll
    for (int i = 0; i < FPC / 2; ++i) T.v[i] = l2[i];
  }

  const float* p = P.f;
  const float* t = T.f;

  // ---- per-cell loss ----
  const float gx = (float)(cell % S);
  const float gy = (float)((cell / S) % S);
  const float mask = (t[9] > 0.0f) ? 1.0f : 0.0f;

  float iou[2];
  #pragma unroll
  for (int b = 0; b < 2; ++b) {
    const float* pb = p + 5 * b;
    const float* tb = t + 5 * b;
    // _convert_boxes: x0=(x+gx)*STEP - w/2, clip all 4 at 0
    float px = fmaxf((pb[0] + gx) * STEP - pb[2] * 0.5f, 0.0f);
    float py = fmaxf((pb[1] + gy) * STEP - pb[3] * 0.5f, 0.0f);
    float pw = fmaxf(pb[2], 0.0f);
    float ph = fmaxf(pb[3], 0.0f);
    float tx = fmaxf((tb[0] + gx) * STEP - tb[2] * 0.5f, 0.0f);
    float ty = fmaxf((tb[1] + gy) * STEP - tb[3] * 0.5f, 0.0f);
    float tw = fmaxf(tb[2], 0.0f);
    float th = fmaxf(tb[3], 0.0f);
    float iw = fmaxf(pw + tw - (fmaxf(px + pw, tx + tw) - fminf(px, tx)), 0.0f);
    float ih = fmaxf(ph + th - (fmaxf(py + ph, ty + th) - fminf(py, ty)), 0.0f);
    float inter = iw * ih;
    float uni = pw * ph + tw * th - inter;
    iou[b] = inter / (uni + EPS);
  }
  // jnp.argmax: first max wins → box 0 on tie
  const int best = (iou[1] > iou[0]) ? 1 : 0;

  float loss = 0.0f;
  #pragma unroll
  for (int b = 0; b < 2; ++b) {
    const float* pb = p + 5 * b;
    const float* tb = t + 5 * b;
    float obj = (b == best) ? mask : 0.0f;
    float d0 = pb[0] - tb[0];
    float d1 = pb[1] - tb[1];
    float d2 = pb[2] - tb[2];
    float d3 = pb[3] - tb[3];
    loss += 5.0f * obj * (d0 * d0 + d1 * d1 + d2 * d2 + d3 * d3);  // coord
    float dc = pb[4] - iou[b];
    loss += obj * dc * dc;                                         // conf
    loss += 0.5f * (1.0f - obj) * pb[4] * pb[4];                   // noobj
  }
  float cls = 0.0f;
  #pragma unroll
  for (int k = 10; k < 30; ++k) {
    float d = p[k] - t[k];
    cls += d * d;
  }
  loss += mask * cls;                                              // class

  // ---- reduce: wave shuffle → LDS → one atomic per block ----
  #pragma unroll
  for (int off = 32; off > 0; off >>= 1)
    loss += __shfl_down(loss, off, 64);
  if ((tid & 63) == 0) wsum[wid] = loss;
  __syncthreads();
  if (tid == 0) {
    float total = 0.0f;
    #pragma unroll
    for (int w = 0; w < WAVES; ++w) total += wsum[w];
    atomicAdd(out, total * invN);
  }
}

extern "C" void kernel_launch(void* const* d_in, const int* in_sizes, int n_in,
                              void* d_out, int out_size, void* d_ws, size_t ws_size,
                              hipStream_t stream) {
  const float* pred = (const float*)d_in[0];
  const float* target = (const float*)d_in[1];
  float* out = (float*)d_out;

  const int ncells = in_sizes[0] / FPC;      // 802816
  const int nblocks = ncells / BLK;          // 3136 (exact)
  const float invN = 1.0f / (float)(ncells / (S * S));  // 1/16384

  // d_out is poisoned 0xAA before every launch — zero it (capturable op).
  hipMemsetAsync(out, 0, sizeof(float), stream);
  yolo_loss_kernel<<<nblocks, BLK, 0, stream>>>(pred, target, out, invN);
}

// Round 4
// 206.429 us; speedup vs baseline: 1.0289x; 1.0033x over previous
//
#include <hip/hip_runtime.h>

// YOLO-v1 loss, fp32, N=16384, S=7, B=2, C=20 → 30 floats/cell, 802816 cells.
// R4: kill the single-address atomicAdd. R1-R3 (three different memory
// structures, 17%/62%/40% occupancy) all pinned at 73-79 µs, with replay
// dispatches showing ~0 HBM traffic (L3-hot) at the SAME duration → limiter
// is not memory, it's the 3136 same-address device-scope atomics serializing
// at the cross-XCD coherence point (~23 ns each ≈ 72 µs).
// Fix: per-block partial sums to distinct d_ws slots (plain stores), then a
// single-block reduce kernel. No atomics anywhere.

constexpr int S = 7;
constexpr int FPC = 30;           // floats per cell
constexpr int BLK = 256;          // 4 waves
constexpr int WAVES = BLK / 64;
constexpr int TILE_F4 = 64 * FPC / 4;   // 480 float4 per wave tile
constexpr float STEP = 1.0f / 7.0f;
constexpr float EPS = 1e-10f;

__global__ __launch_bounds__(BLK) void yolo_partial_kernel(
    const float* __restrict__ pred,
    const float* __restrict__ target,
    float* __restrict__ partial) {
  __shared__ float lds[WAVES][64 * FPC];   // 7680 B per wave region
  __shared__ float wsum[WAVES];

  const int tid = threadIdx.x;
  const int lane = tid & 63;
  const int wid = tid >> 6;
  const int cellw = blockIdx.x * BLK + wid * 64;  // wave's first cell
  const int cell = cellw + lane;

  float* myld = lds[wid];
  union Buf { float2 v[FPC / 2]; float f[FPC]; };
  Buf P, T;

  // ---- stage pred tile: dense float4, wave-private, no barrier ----
  {
    const float4* g = (const float4*)(pred + (size_t)cellw * FPC);
    float4* l = (float4*)myld;
    #pragma unroll
    for (int it = 0; it < (TILE_F4 + 63) / 64; ++it) {
      int idx = it * 64 + lane;
      if (idx < TILE_F4) l[idx] = g[idx];
    }
  }
  {
    const float2* l2 = (const float2*)(myld + lane * FPC);
    #pragma unroll
    for (int i = 0; i < FPC / 2; ++i) P.v[i] = l2[i];
  }
  asm volatile("" ::: "memory");  // keep target-stage writes after pred reads
  // ---- stage target tile into the SAME region (in-order per wave) ----
  {
    const float4* g = (const float4*)(target + (size_t)cellw * FPC);
    float4* l = (float4*)myld;
    #pragma unroll
    for (int it = 0; it < (TILE_F4 + 63) / 64; ++it) {
      int idx = it * 64 + lane;
      if (idx < TILE_F4) l[idx] = g[idx];
    }
  }
  {
    const float2* l2 = (const float2*)(myld + lane * FPC);
    #pragma unroll
    for (int i = 0; i < FPC / 2; ++i) T.v[i] = l2[i];
  }

  const float* p = P.f;
  const float* t = T.f;

  // ---- per-cell loss ----
  const float gx = (float)(cell % S);
  const float gy = (float)((cell / S) % S);
  const float mask = (t[9] > 0.0f) ? 1.0f : 0.0f;

  float iou[2];
  #pragma unroll
  for (int b = 0; b < 2; ++b) {
    const float* pb = p + 5 * b;
    const float* tb = t + 5 * b;
    // _convert_boxes: x0=(x+gx)*STEP - w/2, clip all 4 at 0
    float px = fmaxf((pb[0] + gx) * STEP - pb[2] * 0.5f, 0.0f);
    float py = fmaxf((pb[1] + gy) * STEP - pb[3] * 0.5f, 0.0f);
    float pw = fmaxf(pb[2], 0.0f);
    float ph = fmaxf(pb[3], 0.0f);
    float tx = fmaxf((tb[0] + gx) * STEP - tb[2] * 0.5f, 0.0f);
    float ty = fmaxf((tb[1] + gy) * STEP - tb[3] * 0.5f, 0.0f);
    float tw = fmaxf(tb[2], 0.0f);
    float th = fmaxf(tb[3], 0.0f);
    float iw = fmaxf(pw + tw - (fmaxf(px + pw, tx + tw) - fminf(px, tx)), 0.0f);
    float ih = fmaxf(ph + th - (fmaxf(py + ph, ty + th) - fminf(py, ty)), 0.0f);
    float inter = iw * ih;
    float uni = pw * ph + tw * th - inter;
    iou[b] = inter / (uni + EPS);
  }
  // jnp.argmax: first max wins → box 0 on tie
  const int best = (iou[1] > iou[0]) ? 1 : 0;

  float loss = 0.0f;
  #pragma unroll
  for (int b = 0; b < 2; ++b) {
    const float* pb = p + 5 * b;
    const float* tb = t + 5 * b;
    float obj = (b == best) ? mask : 0.0f;
    float d0 = pb[0] - tb[0];
    float d1 = pb[1] - tb[1];
    float d2 = pb[2] - tb[2];
    float d3 = pb[3] - tb[3];
    loss += 5.0f * obj * (d0 * d0 + d1 * d1 + d2 * d2 + d3 * d3);  // coord
    float dc = pb[4] - iou[b];
    loss += obj * dc * dc;                                         // conf
    loss += 0.5f * (1.0f - obj) * pb[4] * pb[4];                   // noobj
  }
  float cls = 0.0f;
  #pragma unroll
  for (int k = 10; k < 30; ++k) {
    float d = p[k] - t[k];
    cls += d * d;
  }
  loss += mask * cls;                                              // class

  // ---- reduce: wave shuffle → LDS → ONE PLAIN STORE per block ----
  #pragma unroll
  for (int off = 32; off > 0; off >>= 1)
    loss += __shfl_down(loss, off, 64);
  if ((tid & 63) == 0) wsum[wid] = loss;
  __syncthreads();
  if (tid == 0) {
    float total = 0.0f;
    #pragma unroll
    for (int w = 0; w < WAVES; ++w) total += wsum[w];
    partial[blockIdx.x] = total;          // distinct address — no atomic
  }
}

__global__ __launch_bounds__(256) void yolo_reduce_kernel(
    const float* __restrict__ partial, float* __restrict__ out,
    int n, float invN) {
  __shared__ float wsum[4];
  const int tid = threadIdx.x;
  float s = 0.0f;
  for (int i = tid; i < n; i += 256) s += partial[i];
  #pragma unroll
  for (int off = 32; off > 0; off >>= 1)
    s += __shfl_down(s, off, 64);
  if ((tid & 63) == 0) wsum[tid >> 6] = s;
  __syncthreads();
  if (tid == 0)
    out[0] = (wsum[0] + wsum[1] + wsum[2] + wsum[3]) * invN;
}

extern "C" void kernel_launch(void* const* d_in, const int* in_sizes, int n_in,
                              void* d_out, int out_size, void* d_ws, size_t ws_size,
                              hipStream_t stream) {
  const float* pred = (const float*)d_in[0];
  const float* target = (const float*)d_in[1];
  float* out = (float*)d_out;
  float* partial = (float*)d_ws;             // 3136 floats = 12.5 KB

  const int ncells = in_sizes[0] / FPC;      // 802816
  const int nblocks = ncells / BLK;          // 3136 (exact)
  const float invN = 1.0f / (float)(ncells / (S * S));  // 1/16384

  yolo_partial_kernel<<<nblocks, BLK, 0, stream>>>(pred, target, partial);
  yolo_reduce_kernel<<<1, 256, 0, stream>>>(partial, out, nblocks, invN);
}